// Round 12
// baseline (345.195 us; speedup 1.0000x reference)
//
#include <hip/hip_runtime.h>
#include <hip/hip_bf16.h>

// Problem constants (M is a static constant in the reference; N,E derived from in_sizes)
#define D 128
#define MSEG 10000
#define CB 64        // coarse buckets per direction
#define CAP 16384    // pairs capacity per bucket region (expected ~7812, 2.1x headroom)

typedef __attribute__((ext_vector_type(8))) __bf16 bf16x8;
typedef __attribute__((ext_vector_type(4))) float f32x4;

// NOTE: the reference's `col - min(col)` is a pure relabeling of segment ids.
// e_feat/e_proj are produced and consumed through the same id map, so the output
// is invariant — we skip the min entirely (col values are already in [0, M)).
//
// CSR build: destination-ordered two-pass. Measured HW law (R3/R6/R8): scattered
// 4-8B stores cost ~32B HBM write each; block-contiguous >=64B runs write ~1x.
// R12: segment-mean aggregation fused INTO the consuming GEMMs (means land in LDS
// in MFMA A-chunk layout; W staged per-chunk since it has no cross-chunk reuse).

__device__ __forceinline__ int cbkt(int c, int M) { return (c * CB) / M; }
__device__ __forceinline__ int rbkt(int r, int N) { return (int)(((long long)r * CB) / N); }

// ---- async global->LDS 16B DMA (m97 pattern). LDS dst must be wave-uniform base
// + lane*16 in lane order — all our staging layouts satisfy this.
#if __has_builtin(__builtin_amdgcn_global_load_lds)
typedef __attribute__((address_space(1))) const unsigned int gu32;
typedef __attribute__((address_space(3))) unsigned int lu32;
__device__ __forceinline__ void dma16(const void* g, void* l) {
    __builtin_amdgcn_global_load_lds((gu32*)g, (lu32*)l, 16, 0, 0);
}
#else
__device__ __forceinline__ void dma16(const void* g, void* l) {
    *(bf16x8*)l = *(const bf16x8*)g;
}
#endif

// ---------------- W pre-convert (f32 -> bf16 planes) + bucket cursor init ----------------
// wp layout: [Wv 16 planes | We 16 planes | Wu 32 planes], plane = 128 cols x 8 k,
// element (p,c,j) at ((p*128)+c)*8+j  ==  W[p*8+j][c].
__global__ __launch_bounds__(256) void prep_w(const float* __restrict__ Wv, const float* __restrict__ We,
                                              const float* __restrict__ Wu, __bf16* __restrict__ wp,
                                              int* __restrict__ gcursor) {
    if (blockIdx.x == 0 && threadIdx.x < 128)
        gcursor[threadIdx.x] = (threadIdx.x & 63) * CAP;   // region base within each dir's bins
    int idx = blockIdx.x * 256 + threadIdx.x;   // (p_global, c): 64*128 = 8192
    if (idx >= 8192) return;
    int pg = idx >> 7;
    int c = idx & 127;
    const float* src; int pl;
    if (pg < 16)      { src = Wv; pl = pg; }
    else if (pg < 32) { src = We; pl = pg - 16; }
    else              { src = Wu; pl = pg - 32; }
    union { bf16x8 v; __bf16 e[8]; } u;
    #pragma unroll
    for (int j = 0; j < 8; ++j) u.e[j] = (__bf16)src[(pl * 8 + j) * 128 + c];
    *(bf16x8*)&wp[(size_t)idx * 8] = u.v;
}

// ---------------- FUSED: gemm_v (blocks [0,NGB)) | counting scatter (blocks [NGB, ...)) -----
__global__ __launch_bounds__(256) void gemmv_scatter(
        const float* __restrict__ A0v, const __bf16* __restrict__ Wp, __bf16* __restrict__ xp, int rows, int NGB,
        const int* __restrict__ row, const int* __restrict__ col, int n, int* __restrict__ gcursor,
        int2* __restrict__ cbins, int2* __restrict__ rbins, int M, int N) {
    __shared__ __bf16 Ws[16 * 128 * 8];   // 32KB
    __shared__ __bf16 As[2][4 * 128 * 8]; // 16KB
    __shared__ int lcur[128];
    int tid = threadIdx.x;

    if ((int)blockIdx.x >= NGB) {
        // ======== scatter branch: 2048 pairs/block, one reservation per bucket per block
        if (tid < 128) lcur[tid] = 0;
        __syncthreads();
        int base = (blockIdx.x - NGB) * 2048;
        int cc[8], rr[8], bc[8], br[8];
        #pragma unroll
        for (int u = 0; u < 8; ++u) {
            int i = base + u * 256 + tid;
            if (i < n) {
                int c = col[i], r = row[i];
                cc[u] = c; rr[u] = r;
                bc[u] = cbkt(c, M);
                br[u] = 64 + rbkt(r, N);
                atomicAdd(&lcur[bc[u]], 1);
                atomicAdd(&lcur[br[u]], 1);
            } else bc[u] = -1;
        }
        __syncthreads();
        if (tid < 128) {
            int cnt = lcur[tid];
            int gb = cnt ? atomicAdd(&gcursor[tid], cnt) : 0;
            lcur[tid] = gb;
        }
        __syncthreads();
        #pragma unroll
        for (int u = 0; u < 8; ++u) {
            if (bc[u] >= 0) {
                int pc = atomicAdd(&lcur[bc[u]], 1);
                if (pc < (bc[u] + 1) * CAP) cbins[pc] = make_int2(cc[u], rr[u]);
                int pr = atomicAdd(&lcur[br[u]], 1);
                int rb = br[u] - 64;
                if (pr < (rb + 1) * CAP) rbins[pr] = make_int2(rr[u], cc[u]);
            }
        }
        return;
    }

    // ======== gemm branch: xp[128x128 tile] = bf16( f32 A tile @ Wv )
    int w = tid >> 6, lane = tid & 63;
    int quad = lane >> 4, l15 = lane & 15;
    int r0 = blockIdx.x * 128;
    int mh = (w >> 1) * 64, nh = (w & 1) * 64;

    #pragma unroll
    for (int it = 0; it < 8; ++it) {
        int idx = it * 256 + tid;
        dma16(Wp + (size_t)idx * 8, &Ws[(size_t)idx * 8]);
    }
    f32x4 acc[4][4];
    {
        f32x4 z = {0.f, 0.f, 0.f, 0.f};
        #pragma unroll
        for (int i = 0; i < 4; ++i)
            #pragma unroll
            for (int j = 0; j < 4; ++j) acc[i][j] = z;
    }
    auto stageA = [&](int t, int b) {
        int k0 = t * 32;
        #pragma unroll
        for (int h = 0; h < 2; ++h) {
            int i = h * 256 + tid;
            int q = i >> 7, r = i & 127;
            int rr2 = min(r0 + r, rows - 1);
            const float* Ap = A0v + (size_t)rr2 * D + k0 + q * 8;
            float4 f0 = *(const float4*)Ap;
            float4 f1 = *(const float4*)(Ap + 4);
            union { bf16x8 v; __bf16 e[8]; } u;
            u.e[0] = (__bf16)f0.x; u.e[1] = (__bf16)f0.y; u.e[2] = (__bf16)f0.z; u.e[3] = (__bf16)f0.w;
            u.e[4] = (__bf16)f1.x; u.e[5] = (__bf16)f1.y; u.e[6] = (__bf16)f1.z; u.e[7] = (__bf16)f1.w;
            *(bf16x8*)&As[b][i * 8] = u.v;
        }
    };
    stageA(0, 0);
    for (int t = 0; t < 4; ++t) {
        __syncthreads();
        if (t + 1 < 4) stageA(t + 1, (t + 1) & 1);
        int b = t & 1;
        bf16x8 af[4], bfr[4];
        #pragma unroll
        for (int mi = 0; mi < 4; ++mi)
            af[mi] = *(const bf16x8*)&As[b][(quad * 128 + mh + mi * 16 + l15) * 8];
        #pragma unroll
        for (int ni = 0; ni < 4; ++ni)
            bfr[ni] = *(const bf16x8*)&Ws[((t * 4 + quad) * 128 + nh + ni * 16 + l15) * 8];
        #pragma unroll
        for (int mi = 0; mi < 4; ++mi)
            #pragma unroll
            for (int ni = 0; ni < 4; ++ni)
                acc[mi][ni] = __builtin_amdgcn_mfma_f32_16x16x32_bf16(af[mi], bfr[ni], acc[mi][ni], 0, 0, 0);
    }
    #pragma unroll
    for (int ni = 0; ni < 4; ++ni) {
        int colc = nh + ni * 16 + l15;
        #pragma unroll
        for (int mi = 0; mi < 4; ++mi) {
            #pragma unroll
            for (int v = 0; v < 4; ++v) {
                int r = r0 + mh + mi * 16 + quad * 4 + v;
                if (r < rows) xp[(size_t)r * D + colc] = (__bf16)acc[mi][ni][v];
            }
        }
    }
}

// ---------------- build CSR: one block per bucket, exclusive destination slice --------------
__global__ __launch_bounds__(512) void build_csr(const int2* __restrict__ cbins, const int2* __restrict__ rbins,
                                                 const int* __restrict__ gcursor,
                                                 int* __restrict__ coff, int* __restrict__ roff,
                                                 int* __restrict__ clist, int* __restrict__ rlist,
                                                 int M, int N, int E_) {
    __shared__ int hist[800];
    __shared__ int cur[800];
    __shared__ int wsum2[8];
    __shared__ int sbase, scnt;
    int b = blockIdx.x, tid = threadIdx.x;
    int dir = b >> 6, bb = b & 63;
    int tot = dir ? N : M;
    int lo = (bb * tot + CB - 1) / CB;            // ceil(bb*tot/64): first key in bucket
    int hi = ((bb + 1) * tot + CB - 1) / CB;
    int nb = hi - lo;                             // <= 782
    if (tid < 64) {                               // wave 0: per-dir prefix over bucket counts
        int cnt_l = min(gcursor[dir * 64 + tid] - tid * CAP, CAP);
        int incl = cnt_l;
        #pragma unroll
        for (int o = 1; o < 64; o <<= 1) { int t = __shfl_up(incl, o, 64); if (tid >= o) incl += t; }
        if (tid == bb) { sbase = incl - cnt_l; scnt = cnt_l; }
    }
    for (int i = tid; i < nb; i += 512) hist[i] = 0;
    __syncthreads();
    int bcnt = scnt;
    int bstart = sbase;                           // CSR offset of this bucket
    const int2* bins = (dir ? rbins : cbins) + (size_t)bb * CAP;
    int* offp = dir ? roff : coff;
    int* list = dir ? rlist : clist;
    for (int i = tid; i < bcnt; i += 512) {
        int2 pr = bins[i];
        atomicAdd(&hist[pr.x - lo], 1);
    }
    __syncthreads();
    // block exclusive scan over hist[0..nb), 2 elems/thread (512*2 >= 800)
    int lane = tid & 63, wv = tid >> 6;
    int i0 = tid * 2;
    int a0 = (i0     < nb) ? hist[i0]     : 0;
    int a1 = (i0 + 1 < nb) ? hist[i0 + 1] : 0;
    int ts = a0 + a1;
    int incl = ts;
    #pragma unroll
    for (int o = 1; o < 64; o <<= 1) { int t = __shfl_up(incl, o, 64); if (lane >= o) incl += t; }
    if (lane == 63) wsum2[wv] = incl;
    int wex = incl - ts;
    __syncthreads();
    int wb = 0;
    for (int j = 0; j < wv; ++j) wb += wsum2[j];
    int tb = bstart + wb + wex;
    if (i0     < nb) { offp[lo + i0]     = tb;      cur[i0]     = tb; }
    if (i0 + 1 < nb) { offp[lo + i0 + 1] = tb + a0; cur[i0 + 1] = tb + a0; }
    __syncthreads();
    for (int i = tid; i < bcnt; i += 512) {
        int2 pr = bins[i];
        int p = atomicAdd(&cur[pr.x - lo], 1);
        list[p] = pr.y;                           // block-exclusive ~31KB region
    }
    if (b == 0 && tid == 0) { coff[M] = E_; roff[N] = E_; }
}

// ---- shared gather helper: compute segment means into LDS in MFMA A-chunk layout ----
// mbuf region: t*4096 + (q*128 + r)*8 + j  holds channel c = t*32+q*8+j of local row r.
// Lane (slot=lane>>4, cg=lane&15) covers channels cg*8..+7 -> t=cg>>2, q=cg&3.
__device__ __forceinline__ void gather_means(const __bf16* __restrict__ src, const int* __restrict__ off,
                                             const int* __restrict__ list, int s0, int nseg,
                                             __bf16* __restrict__ mbuf, int tid) {
    int lane = tid & 63, w = tid >> 6;
    int slot = lane >> 4, cg = lane & 15;
    int dst_base = (cg >> 2) * 4096 + (cg & 3) * 128 * 8;
    for (int k = 0; k < 32; ++k) {
        int seg_i = w + 4 * k;                    // interleaved across waves
        int seg = s0 + seg_i;
        float acc[8];
        #pragma unroll
        for (int j = 0; j < 8; ++j) acc[j] = 0.f;
        int cnt = 0;
        if (seg < nseg) {
            int s = off[seg], e = off[seg + 1];
            cnt = e - s;
            int i = s;
            for (; i + 8 <= e; i += 8) {
                int r0 = list[i + slot];
                int r1 = list[i + 4 + slot];
                bf16x8 v0 = *(const bf16x8*)&src[(size_t)r0 * D + cg * 8];
                bf16x8 v1 = *(const bf16x8*)&src[(size_t)r1 * D + cg * 8];
                #pragma unroll
                for (int j = 0; j < 8; ++j) acc[j] += (float)v0[j] + (float)v1[j];
            }
            for (; i < e; i += 4) {
                int ii = i + slot;
                if (ii < e) {
                    int r = list[ii];
                    bf16x8 v = *(const bf16x8*)&src[(size_t)r * D + cg * 8];
                    #pragma unroll
                    for (int j = 0; j < 8; ++j) acc[j] += (float)v[j];
                }
            }
        }
        #pragma unroll
        for (int j = 0; j < 8; ++j) {
            acc[j] += __shfl_xor(acc[j], 16, 64);
            acc[j] += __shfl_xor(acc[j], 32, 64);
        }
        if (slot == 0) {
            float inv = 1.f / (float)max(cnt, 1);
            union { bf16x8 v; __bf16 e[8]; } u;
            #pragma unroll
            for (int j = 0; j < 8; ++j) u.e[j] = (__bf16)(acc[j] * inv);
            *(bf16x8*)&mbuf[dst_base + seg_i * 8] = u.v;
        }
    }
}

// ---------------- FUSED agg+gemm_e: e_proj[seg tile] = bf16( mean_tile @ We ) ---------------
// Means land in LDS (A-chunk layout); We staged per 32-k chunk (no cross-chunk reuse).
__global__ __launch_bounds__(256) void agg_gemm_e(const __bf16* __restrict__ xp, const int* __restrict__ coff,
                                                  const int* __restrict__ clist, const __bf16* __restrict__ Wp,
                                                  __bf16* __restrict__ e_proj, int nseg) {
    __shared__ __bf16 mbuf[4 * 4 * 128 * 8];   // 32KB: 128 segment means, chunk layout
    __shared__ __bf16 Ws[2][4 * 128 * 8];      // 2 x 8KB: W chunk planes
    int tid = threadIdx.x;
    int w = tid >> 6, lane = tid & 63;
    int quad = lane >> 4, l15 = lane & 15;
    int s0 = blockIdx.x * 128;
    int mh = (w >> 1) * 64, nh = (w & 1) * 64;

    auto stageW = [&](int t, int b) {           // 4 planes = 4096 elems = 2 dma16/thread
        #pragma unroll
        for (int h = 0; h < 2; ++h) {
            int idx = h * 256 + tid;            // bf16x8 units within chunk
            dma16(Wp + ((size_t)t * 512 + idx) * 8, &Ws[b][(size_t)idx * 8]);
        }
    };
    stageW(0, 0);                               // in flight during the gather
    gather_means(xp, coff, clist, s0, nseg, mbuf, tid);

    f32x4 acc[4][4];
    {
        f32x4 z = {0.f, 0.f, 0.f, 0.f};
        #pragma unroll
        for (int i = 0; i < 4; ++i)
            #pragma unroll
            for (int j = 0; j < 4; ++j) acc[i][j] = z;
    }
    for (int t = 0; t < 4; ++t) {
        __syncthreads();                        // drains Ws(t) DMA; protects mbuf (t=0)
        if (t + 1 < 4) stageW(t + 1, (t + 1) & 1);
        int b = t & 1;
        bf16x8 af[4], bfr[4];
        #pragma unroll
        for (int mi = 0; mi < 4; ++mi)
            af[mi] = *(const bf16x8*)&mbuf[t * 4096 + (quad * 128 + mh + mi * 16 + l15) * 8];
        #pragma unroll
        for (int ni = 0; ni < 4; ++ni)
            bfr[ni] = *(const bf16x8*)&Ws[b][(quad * 128 + nh + ni * 16 + l15) * 8];
        #pragma unroll
        for (int mi = 0; mi < 4; ++mi)
            #pragma unroll
            for (int ni = 0; ni < 4; ++ni)
                acc[mi][ni] = __builtin_amdgcn_mfma_f32_16x16x32_bf16(af[mi], bfr[ni], acc[mi][ni], 0, 0, 0);
    }
    #pragma unroll
    for (int ni = 0; ni < 4; ++ni) {
        int colc = nh + ni * 16 + l15;
        #pragma unroll
        for (int mi = 0; mi < 4; ++mi) {
            #pragma unroll
            for (int v = 0; v < 4; ++v) {
                int r = s0 + mh + mi * 16 + quad * 4 + v;
                if (r < nseg) e_proj[(size_t)r * D + colc] = (__bf16)acc[mi][ni][v];
            }
        }
    }
}

// ---------------- FUSED agg+gemm_u: out = relu( concat(xp, mean(e_proj)) @ Wu + bu ) --------
// LDS: mbuf 32KB (n_agg means, K-chunks 4..7) + As 2x8KB (xp chunks 0..3) + Ws 2x8KB = 64KB.
__global__ __launch_bounds__(256) void agg_gemm_u(const __bf16* __restrict__ xp, const __bf16* __restrict__ e_proj,
                                                  const int* __restrict__ roff, const int* __restrict__ rlist,
                                                  const __bf16* __restrict__ Wp, const float* __restrict__ bias,
                                                  float* __restrict__ out, int rows) {
    __shared__ __bf16 mbuf[4 * 4 * 128 * 8];   // 32KB
    __shared__ __bf16 As[2][4 * 128 * 8];      // 16KB
    __shared__ __bf16 Ws[2][4 * 128 * 8];      // 16KB  (total 64KB exactly)
    int tid = threadIdx.x;
    int w = tid >> 6, lane = tid & 63;
    int quad = lane >> 4, l15 = lane & 15;
    int r0 = blockIdx.x * 128;
    int mh = (w >> 1) * 64, nh = (w & 1) * 64;

    auto stageW = [&](int t, int b) {
        #pragma unroll
        for (int h = 0; h < 2; ++h) {
            int idx = h * 256 + tid;
            dma16(Wp + ((size_t)t * 512 + idx) * 8, &Ws[b][(size_t)idx * 8]);
        }
    };
    auto stageA = [&](int t, int b) {           // xp chunk t (t<4)
        int k0 = t * 32;
        #pragma unroll
        for (int h = 0; h < 2; ++h) {
            int i = h * 256 + tid;
            int q = i >> 7, r = i & 127;
            int rr = min(r0 + r, rows - 1);
            dma16(xp + (size_t)rr * D + k0 + q * 8, &As[b][i * 8]);
        }
    };
    stageW(0, 0);
    stageA(0, 0);                               // in flight during the gather
    gather_means(e_proj, roff, rlist, r0, rows, mbuf, tid);

    f32x4 acc[4][4];
    {
        f32x4 z = {0.f, 0.f, 0.f, 0.f};
        #pragma unroll
        for (int i = 0; i < 4; ++i)
            #pragma unroll
            for (int j = 0; j < 4; ++j) acc[i][j] = z;
    }
    for (int t = 0; t < 8; ++t) {
        __syncthreads();                        // drains DMA for chunk t; protects mbuf (t=0)
        if (t + 1 < 8) {
            stageW(t + 1, (t + 1) & 1);
            if (t + 1 < 4) stageA(t + 1, (t + 1) & 1);
        }
        int b = t & 1;
        bf16x8 af[4], bfr[4];
        #pragma unroll
        for (int mi = 0; mi < 4; ++mi) {
            if (t < 4)
                af[mi] = *(const bf16x8*)&As[b][(quad * 128 + mh + mi * 16 + l15) * 8];
            else
                af[mi] = *(const bf16x8*)&mbuf[(t - 4) * 4096 + (quad * 128 + mh + mi * 16 + l15) * 8];
        }
        #pragma unroll
        for (int ni = 0; ni < 4; ++ni)
            bfr[ni] = *(const bf16x8*)&Ws[b][(quad * 128 + nh + ni * 16 + l15) * 8];
        #pragma unroll
        for (int mi = 0; mi < 4; ++mi)
            #pragma unroll
            for (int ni = 0; ni < 4; ++ni)
                acc[mi][ni] = __builtin_amdgcn_mfma_f32_16x16x32_bf16(af[mi], bfr[ni], acc[mi][ni], 0, 0, 0);
    }
    #pragma unroll
    for (int ni = 0; ni < 4; ++ni) {
        int colc = nh + ni * 16 + l15;
        float bv = bias[colc];
        #pragma unroll
        for (int mi = 0; mi < 4; ++mi) {
            #pragma unroll
            for (int v = 0; v < 4; ++v) {
                int r = r0 + mh + mi * 16 + quad * 4 + v;
                if (r < rows) out[(size_t)r * D + colc] = fmaxf(acc[mi][ni][v] + bv, 0.f);
            }
        }
    }
}

extern "C" void kernel_launch(void* const* d_in, const int* in_sizes, int n_in,
                              void* d_out, int out_size, void* d_ws, size_t ws_size,
                              hipStream_t stream) {
    const float* x  = (const float*)d_in[0];
    const int*   ei = (const int*)d_in[1];
    const float* Wv = (const float*)d_in[2];
    const float* We = (const float*)d_in[3];
    const float* Wu = (const float*)d_in[4];
    const float* bu = (const float*)d_in[5];
    float* out = (float*)d_out;

    const int N = in_sizes[0] / D;       // 50000
    const int E = in_sizes[1] / 2;       // 500000
    const int M = MSEG;                  // 10000 (static in reference)
    const int* row = ei;
    const int* col = ei + E;

    // workspace carve-out (256B aligned)
    char* p = (char*)d_ws;
    auto alloc = [&](size_t bytes) { char* q = p; p += (bytes + 255) & ~(size_t)255; return q; };
    __bf16* xp     = (__bf16*)alloc((size_t)N * D * 2);   // 12.8MB
    __bf16* e_proj = (__bf16*)alloc((size_t)M * D * 2);   // 2.56MB
    __bf16* wp     = (__bf16*)alloc((size_t)64 * 128 * 8 * 2);   // 128KB plane-layout W
    int* coff  = (int*)alloc((size_t)(M + 1) * 4);
    int* roff  = (int*)alloc((size_t)(N + 1) * 4);
    int* clist = (int*)alloc((size_t)E * 4);
    int* rlist = (int*)alloc((size_t)E * 4);
    int2* cbins = (int2*)alloc((size_t)64 * CAP * 8);     // 8MB (no aliasing: gemm_v runs
    int2* rbins = (int2*)alloc((size_t)64 * CAP * 8);     // 8MB  concurrently with scatter)
    int* gcursor = (int*)alloc(512);

    const int NGB = (N + 127) / 128;     // gemm_v blocks
    const int SB  = (E + 2047) / 2048;   // scatter blocks

    prep_w<<<32, 256, 0, stream>>>(Wv, We, Wu, wp, gcursor);
    gemmv_scatter<<<NGB + SB, 256, 0, stream>>>(x, wp, xp, N, NGB,
                                                row, col, E, gcursor, cbins, rbins, M, N);
    build_csr<<<128, 512, 0, stream>>>(cbins, rbins, gcursor, coff, roff, clist, rlist, M, N, E);
    agg_gemm_e<<<(M + 127) / 128, 256, 0, stream>>>(xp, coff, clist, wp + 16384, e_proj, M);
    agg_gemm_u<<<(N + 127) / 128, 256, 0, stream>>>(xp, e_proj, roff, rlist, wp + 32768, bu, out, N);
}

// Round 13
// 176.573 us; speedup vs baseline: 1.9550x; 1.9550x over previous
//
#include <hip/hip_runtime.h>
#include <hip/hip_bf16.h>

// Problem constants (M is a static constant in the reference; N,E derived from in_sizes)
#define D 128
#define MSEG 10000
#define CB 64        // coarse buckets per direction
#define CAP 16384    // pairs capacity per bucket region (expected ~7812, 2.1x headroom)

typedef __attribute__((ext_vector_type(8))) __bf16 bf16x8;
typedef __attribute__((ext_vector_type(4))) float f32x4;

// NOTE: the reference's `col - min(col)` is a pure relabeling of segment ids.
// e_feat/e_proj are produced and consumed through the same id map, so the output
// is invariant — we skip the min entirely (col values are already in [0, M)).
//
// R13: revert R12's agg+gemm fusion (it collapsed the gather to 79 blocks ->
// 316 waves -> 170us latency-bound; R11's 10000-wave agg_mean is the right
// shape). Keep R12's per-chunk double-buffered W staging in the GEMMs
// (LDS 80KB->32KB, occupancy 2->~5 blocks/CU). Overlap the r-direction CSR
// build under the M-direction aggregation (independent work).

__device__ __forceinline__ int cbkt(int c, int M) { return (c * CB) / M; }
__device__ __forceinline__ int rbkt(int r, int N) { return (int)(((long long)r * CB) / N); }

#if __has_builtin(__builtin_amdgcn_global_load_lds)
typedef __attribute__((address_space(1))) const unsigned int gu32;
typedef __attribute__((address_space(3))) unsigned int lu32;
__device__ __forceinline__ void dma16(const void* g, void* l) {
    __builtin_amdgcn_global_load_lds((gu32*)g, (lu32*)l, 16, 0, 0);
}
#else
__device__ __forceinline__ void dma16(const void* g, void* l) {
    *(bf16x8*)l = *(const bf16x8*)g;
}
#endif

// ---------------- W pre-convert (f32 -> bf16 planes) + bucket cursor init ----------------
__global__ __launch_bounds__(256) void prep_w(const float* __restrict__ Wv, const float* __restrict__ We,
                                              const float* __restrict__ Wu, __bf16* __restrict__ wp,
                                              int* __restrict__ gcursor) {
    if (blockIdx.x == 0 && threadIdx.x < 128)
        gcursor[threadIdx.x] = (threadIdx.x & 63) * CAP;   // region base within each dir's bins
    int idx = blockIdx.x * 256 + threadIdx.x;   // (p_global, c): 64*128 = 8192
    if (idx >= 8192) return;
    int pg = idx >> 7;
    int c = idx & 127;
    const float* src; int pl;
    if (pg < 16)      { src = Wv; pl = pg; }
    else if (pg < 32) { src = We; pl = pg - 16; }
    else              { src = Wu; pl = pg - 32; }
    union { bf16x8 v; __bf16 e[8]; } u;
    #pragma unroll
    for (int j = 0; j < 8; ++j) u.e[j] = (__bf16)src[(pl * 8 + j) * 128 + c];
    *(bf16x8*)&wp[(size_t)idx * 8] = u.v;
}

// ---------------- FUSED: gemm_v (blocks [0,NGB)) | counting scatter (blocks [NGB, ...)) -----
__global__ __launch_bounds__(256) void gemmv_scatter(
        const float* __restrict__ A0v, const __bf16* __restrict__ Wp, __bf16* __restrict__ xp, int rows, int NGB,
        const int* __restrict__ row, const int* __restrict__ col, int n, int* __restrict__ gcursor,
        int2* __restrict__ cbins, int2* __restrict__ rbins, int M, int N) {
    __shared__ __bf16 Ws[16 * 128 * 8];   // 32KB
    __shared__ __bf16 As[2][4 * 128 * 8]; // 16KB
    __shared__ int lcur[128];
    int tid = threadIdx.x;

    if ((int)blockIdx.x >= NGB) {
        // ======== scatter branch: 2048 pairs/block, one reservation per bucket per block
        if (tid < 128) lcur[tid] = 0;
        __syncthreads();
        int base = (blockIdx.x - NGB) * 2048;
        int cc[8], rr[8], bc[8], br[8];
        #pragma unroll
        for (int u = 0; u < 8; ++u) {
            int i = base + u * 256 + tid;
            if (i < n) {
                int c = col[i], r = row[i];
                cc[u] = c; rr[u] = r;
                bc[u] = cbkt(c, M);
                br[u] = 64 + rbkt(r, N);
                atomicAdd(&lcur[bc[u]], 1);
                atomicAdd(&lcur[br[u]], 1);
            } else bc[u] = -1;
        }
        __syncthreads();
        if (tid < 128) {
            int cnt = lcur[tid];
            int gb = cnt ? atomicAdd(&gcursor[tid], cnt) : 0;
            lcur[tid] = gb;
        }
        __syncthreads();
        #pragma unroll
        for (int u = 0; u < 8; ++u) {
            if (bc[u] >= 0) {
                int pc = atomicAdd(&lcur[bc[u]], 1);
                if (pc < (bc[u] + 1) * CAP) cbins[pc] = make_int2(cc[u], rr[u]);
                int pr = atomicAdd(&lcur[br[u]], 1);
                int rb = br[u] - 64;
                if (pr < (rb + 1) * CAP) rbins[pr] = make_int2(rr[u], cc[u]);
            }
        }
        return;
    }

    // ======== gemm branch: xp[128x128 tile] = bf16( f32 A tile @ Wv )
    int w = tid >> 6, lane = tid & 63;
    int quad = lane >> 4, l15 = lane & 15;
    int r0 = blockIdx.x * 128;
    int mh = (w >> 1) * 64, nh = (w & 1) * 64;

    #pragma unroll
    for (int it = 0; it < 8; ++it) {
        int idx = it * 256 + tid;
        dma16(Wp + (size_t)idx * 8, &Ws[(size_t)idx * 8]);
    }
    f32x4 acc[4][4];
    {
        f32x4 z = {0.f, 0.f, 0.f, 0.f};
        #pragma unroll
        for (int i = 0; i < 4; ++i)
            #pragma unroll
            for (int j = 0; j < 4; ++j) acc[i][j] = z;
    }
    auto stageA = [&](int t, int b) {
        int k0 = t * 32;
        #pragma unroll
        for (int h = 0; h < 2; ++h) {
            int i = h * 256 + tid;
            int q = i >> 7, r = i & 127;
            int rr2 = min(r0 + r, rows - 1);
            const float* Ap = A0v + (size_t)rr2 * D + k0 + q * 8;
            float4 f0 = *(const float4*)Ap;
            float4 f1 = *(const float4*)(Ap + 4);
            union { bf16x8 v; __bf16 e[8]; } u;
            u.e[0] = (__bf16)f0.x; u.e[1] = (__bf16)f0.y; u.e[2] = (__bf16)f0.z; u.e[3] = (__bf16)f0.w;
            u.e[4] = (__bf16)f1.x; u.e[5] = (__bf16)f1.y; u.e[6] = (__bf16)f1.z; u.e[7] = (__bf16)f1.w;
            *(bf16x8*)&As[b][i * 8] = u.v;
        }
    };
    stageA(0, 0);
    for (int t = 0; t < 4; ++t) {
        __syncthreads();
        if (t + 1 < 4) stageA(t + 1, (t + 1) & 1);
        int b = t & 1;
        bf16x8 af[4], bfr[4];
        #pragma unroll
        for (int mi = 0; mi < 4; ++mi)
            af[mi] = *(const bf16x8*)&As[b][(quad * 128 + mh + mi * 16 + l15) * 8];
        #pragma unroll
        for (int ni = 0; ni < 4; ++ni)
            bfr[ni] = *(const bf16x8*)&Ws[((t * 4 + quad) * 128 + nh + ni * 16 + l15) * 8];
        #pragma unroll
        for (int mi = 0; mi < 4; ++mi)
            #pragma unroll
            for (int ni = 0; ni < 4; ++ni)
                acc[mi][ni] = __builtin_amdgcn_mfma_f32_16x16x32_bf16(af[mi], bfr[ni], acc[mi][ni], 0, 0, 0);
    }
    #pragma unroll
    for (int ni = 0; ni < 4; ++ni) {
        int colc = nh + ni * 16 + l15;
        #pragma unroll
        for (int mi = 0; mi < 4; ++mi) {
            #pragma unroll
            for (int v = 0; v < 4; ++v) {
                int r = r0 + mh + mi * 16 + quad * 4 + v;
                if (r < rows) xp[(size_t)r * D + colc] = (__bf16)acc[mi][ni][v];
            }
        }
    }
}

// ---------------- bucket CSR build body (one 512-thread block per bucket) ----------------
__device__ void build_bucket(int dir, int bb, const int2* __restrict__ binsAll,
                             const int* __restrict__ gcursor, int* __restrict__ offp,
                             int* __restrict__ list, int tot, int E_) {
    __shared__ int hist[800];
    __shared__ int cur[800];
    __shared__ int wsum2[8];
    __shared__ int sbase, scnt;
    int tid = threadIdx.x;
    int lo = (bb * tot + CB - 1) / CB;            // ceil(bb*tot/64): first key in bucket
    int hi = ((bb + 1) * tot + CB - 1) / CB;
    int nb = hi - lo;                             // <= 782
    if (tid < 64) {                               // wave 0: per-dir prefix over bucket counts
        int cnt_l = min(gcursor[dir * 64 + tid] - tid * CAP, CAP);
        int incl = cnt_l;
        #pragma unroll
        for (int o = 1; o < 64; o <<= 1) { int t = __shfl_up(incl, o, 64); if (tid >= o) incl += t; }
        if (tid == bb) { sbase = incl - cnt_l; scnt = cnt_l; }
    }
    for (int i = tid; i < nb; i += 512) hist[i] = 0;
    __syncthreads();
    int bcnt = scnt;
    int bstart = sbase;                           // CSR offset of this bucket
    const int2* bins = binsAll + (size_t)bb * CAP;
    for (int i = tid; i < bcnt; i += 512) {
        int2 pr = bins[i];
        atomicAdd(&hist[pr.x - lo], 1);
    }
    __syncthreads();
    // block exclusive scan over hist[0..nb), 2 elems/thread (512*2 >= 800)
    int lane = tid & 63, wv = tid >> 6;
    int i0 = tid * 2;
    int a0 = (i0     < nb) ? hist[i0]     : 0;
    int a1 = (i0 + 1 < nb) ? hist[i0 + 1] : 0;
    int ts = a0 + a1;
    int incl = ts;
    #pragma unroll
    for (int o = 1; o < 64; o <<= 1) { int t = __shfl_up(incl, o, 64); if (lane >= o) incl += t; }
    if (lane == 63) wsum2[wv] = incl;
    int wex = incl - ts;
    __syncthreads();
    int wb = 0;
    for (int j = 0; j < wv; ++j) wb += wsum2[j];
    int tb = bstart + wb + wex;
    if (i0     < nb) { offp[lo + i0]     = tb;      cur[i0]     = tb; }
    if (i0 + 1 < nb) { offp[lo + i0 + 1] = tb + a0; cur[i0 + 1] = tb + a0; }
    __syncthreads();
    for (int i = tid; i < bcnt; i += 512) {
        int2 pr = bins[i];
        int p = atomicAdd(&cur[pr.x - lo], 1);
        list[p] = pr.y;                           // block-exclusive ~31KB region
    }
    if (bb == 0 && tid == 0) offp[tot] = E_;
}

// ---------------- build c-direction (64 blocks) ----------------
__global__ __launch_bounds__(512) void build_c(const int2* __restrict__ cbins, const int* __restrict__ gcursor,
                                               int* __restrict__ coff, int* __restrict__ clist,
                                               int M, int E_) {
    build_bucket(0, blockIdx.x, cbins, gcursor, coff, clist, M, E_);
}

// ---- per-wave segment mean: lane = (slot=lane>>4 row-slot, cg=lane&15 channel-octet) ----
__device__ __forceinline__ void agg_seg(const __bf16* __restrict__ src, const int* __restrict__ off,
                                        const int* __restrict__ list, __bf16* __restrict__ dst,
                                        int seg, int lane) {
    int slot = lane >> 4, cg = lane & 15;
    int s = off[seg], e = off[seg + 1];
    int cnt = e - s;
    float acc[8];
    #pragma unroll
    for (int j = 0; j < 8; ++j) acc[j] = 0.f;
    int i = s;
    for (; i + 8 <= e; i += 8) {
        int r0 = list[i + slot];
        int r1 = list[i + 4 + slot];
        bf16x8 v0 = *(const bf16x8*)&src[(size_t)r0 * D + cg * 8];
        bf16x8 v1 = *(const bf16x8*)&src[(size_t)r1 * D + cg * 8];
        #pragma unroll
        for (int j = 0; j < 8; ++j) acc[j] += (float)v0[j] + (float)v1[j];
    }
    for (; i < e; i += 4) {
        int ii = i + slot;
        if (ii < e) {
            int r = list[ii];
            bf16x8 v = *(const bf16x8*)&src[(size_t)r * D + cg * 8];
            #pragma unroll
            for (int j = 0; j < 8; ++j) acc[j] += (float)v[j];
        }
    }
    #pragma unroll
    for (int j = 0; j < 8; ++j) {
        acc[j] += __shfl_xor(acc[j], 16, 64);
        acc[j] += __shfl_xor(acc[j], 32, 64);
    }
    if (slot == 0) {
        float inv = 1.f / (float)max(cnt, 1);
        union { bf16x8 v; __bf16 e[8]; } u;
        #pragma unroll
        for (int j = 0; j < 8; ++j) u.e[j] = (__bf16)(acc[j] * inv);
        *(bf16x8*)&dst[(size_t)seg * D + cg * 8] = u.v;
    }
}

// ---------------- FUSED: build_r (blocks 0..63) | agg_mean M (blocks 64..) ----------------
// Independent work items at the same pipeline point; build_r hides under the M-gather.
__global__ __launch_bounds__(512) void aggm_buildr(
        const int2* __restrict__ rbins, const int* __restrict__ gcursor,
        int* __restrict__ roff, int* __restrict__ rlist, int N, int E_,
        const __bf16* __restrict__ xp, const int* __restrict__ coff,
        const int* __restrict__ clist, __bf16* __restrict__ e_feat, int M) {
    if (blockIdx.x < 64) {
        build_bucket(1, blockIdx.x, rbins, gcursor, roff, rlist, N, E_);
        return;
    }
    int seg = (blockIdx.x - 64) * 8 + (threadIdx.x >> 6);   // 8 waves, 1 segment each
    if (seg >= M) return;
    agg_seg(xp, coff, clist, e_feat, seg, threadIdx.x & 63);
}

// ---------------- agg_mean (N direction): one wave per segment, 4 segs/block ----------------
__global__ __launch_bounds__(256) void agg_mean(const __bf16* __restrict__ src, const int* __restrict__ off,
                                                const int* __restrict__ list, __bf16* __restrict__ dst,
                                                int nseg) {
    int seg = blockIdx.x * 4 + (threadIdx.x >> 6);
    if (seg >= nseg) return;
    agg_seg(src, off, list, dst, seg, threadIdx.x & 63);
}

// ---------------- MFMA bf16 GEMM, per-chunk double-buffered W staging (R12 structure) -------
// LDS = As 2x8KB + Ws 2x8KB = 32KB -> ~5 blocks/CU (vs 2 at full-W staging).
template<int NCHUNK, bool FINAL>
__global__ __launch_bounds__(256) void gemm_mfma(const __bf16* __restrict__ A0,
                                                 const __bf16* __restrict__ A1,
                                                 const __bf16* __restrict__ Wp,
                                                 const float* __restrict__ bias,
                                                 void* __restrict__ Cv, int rows) {
    __shared__ __bf16 As[2][4 * 128 * 8];      // 2 x 8KB
    __shared__ __bf16 Ws[2][4 * 128 * 8];      // 2 x 8KB
    int tid = threadIdx.x;
    int w = tid >> 6, lane = tid & 63;
    int quad = lane >> 4, l15 = lane & 15;
    int r0 = blockIdx.x * 128;
    int mh = (w >> 1) * 64, nh = (w & 1) * 64;

    auto stageW = [&](int t, int b) {           // chunk t = 4 planes = 512 bf16x8 units
        #pragma unroll
        for (int h = 0; h < 2; ++h) {
            int idx = h * 256 + tid;
            dma16(Wp + ((size_t)t * 512 + idx) * 8, &Ws[b][(size_t)idx * 8]);
        }
    };
    auto stageA = [&](int t, int b) {
        const __bf16* A = (NCHUNK == 2 && t >= 4) ? A1 : A0;
        int k0 = (t & 3) * 32;
        #pragma unroll
        for (int h = 0; h < 2; ++h) {
            int i = h * 256 + tid;
            int q = i >> 7, r = i & 127;
            int rr = min(r0 + r, rows - 1);
            dma16(A + (size_t)rr * D + k0 + q * 8, &As[b][i * 8]);
        }
    };
    stageW(0, 0);
    stageA(0, 0);

    f32x4 acc[4][4];
    {
        f32x4 z = {0.f, 0.f, 0.f, 0.f};
        #pragma unroll
        for (int i = 0; i < 4; ++i)
            #pragma unroll
            for (int j = 0; j < 4; ++j) acc[i][j] = z;
    }
    const int T = NCHUNK * 4;
    for (int t = 0; t < T; ++t) {
        __syncthreads();                        // drains DMA for chunk t
        if (t + 1 < T) { stageW(t + 1, (t + 1) & 1); stageA(t + 1, (t + 1) & 1); }
        int b = t & 1;
        bf16x8 af[4], bfr[4];
        #pragma unroll
        for (int mi = 0; mi < 4; ++mi)
            af[mi] = *(const bf16x8*)&As[b][(quad * 128 + mh + mi * 16 + l15) * 8];
        #pragma unroll
        for (int ni = 0; ni < 4; ++ni)
            bfr[ni] = *(const bf16x8*)&Ws[b][(quad * 128 + nh + ni * 16 + l15) * 8];
        #pragma unroll
        for (int mi = 0; mi < 4; ++mi)
            #pragma unroll
            for (int ni = 0; ni < 4; ++ni)
                acc[mi][ni] = __builtin_amdgcn_mfma_f32_16x16x32_bf16(af[mi], bfr[ni], acc[mi][ni], 0, 0, 0);
    }

    // epilogue: C/D layout col=lane&15, row=quad*4+reg
    __bf16* Cb = (__bf16*)Cv;
    float* Cf = (float*)Cv;
    #pragma unroll
    for (int ni = 0; ni < 4; ++ni) {
        int colc = nh + ni * 16 + l15;
        float bv = FINAL ? bias[colc] : 0.f;
        #pragma unroll
        for (int mi = 0; mi < 4; ++mi) {
            #pragma unroll
            for (int v = 0; v < 4; ++v) {
                int r = r0 + mh + mi * 16 + quad * 4 + v;
                if (r < rows) {
                    float val = acc[mi][ni][v];
                    if (FINAL) Cf[(size_t)r * D + colc] = fmaxf(val + bv, 0.f);
                    else       Cb[(size_t)r * D + colc] = (__bf16)val;
                }
            }
        }
    }
}

extern "C" void kernel_launch(void* const* d_in, const int* in_sizes, int n_in,
                              void* d_out, int out_size, void* d_ws, size_t ws_size,
                              hipStream_t stream) {
    const float* x  = (const float*)d_in[0];
    const int*   ei = (const int*)d_in[1];
    const float* Wv = (const float*)d_in[2];
    const float* We = (const float*)d_in[3];
    const float* Wu = (const float*)d_in[4];
    const float* bu = (const float*)d_in[5];
    float* out = (float*)d_out;

    const int N = in_sizes[0] / D;       // 50000
    const int E = in_sizes[1] / 2;       // 500000
    const int M = MSEG;                  // 10000 (static in reference)
    const int* row = ei;
    const int* col = ei + E;

    // workspace carve-out (256B aligned)
    char* p = (char*)d_ws;
    auto alloc = [&](size_t bytes) { char* q = p; p += (bytes + 255) & ~(size_t)255; return q; };
    __bf16* xp     = (__bf16*)alloc((size_t)N * D * 2);   // 12.8MB
    __bf16* e_feat = (__bf16*)alloc((size_t)M * D * 2);   // 2.56MB
    __bf16* e_proj = (__bf16*)alloc((size_t)M * D * 2);   // 2.56MB
    __bf16* n_agg  = (__bf16*)alloc((size_t)N * D * 2);   // 12.8MB
    __bf16* wp     = (__bf16*)alloc((size_t)64 * 128 * 8 * 2);   // 128KB plane-layout W
    int* coff  = (int*)alloc((size_t)(M + 1) * 4);
    int* roff  = (int*)alloc((size_t)(N + 1) * 4);
    int* clist = (int*)alloc((size_t)E * 4);
    int* rlist = (int*)alloc((size_t)E * 4);
    int2* cbins = (int2*)alloc((size_t)64 * CAP * 8);     // 8MB (no aliasing: gemm_v runs
    int2* rbins = (int2*)alloc((size_t)64 * CAP * 8);     // 8MB  concurrently with scatter)
    int* gcursor = (int*)alloc(512);

    const int NGB = (N + 127) / 128;     // gemm_v blocks
    const int SB  = (E + 2047) / 2048;   // scatter blocks

    prep_w<<<32, 256, 0, stream>>>(Wv, We, Wu, wp, gcursor);
    gemmv_scatter<<<NGB + SB, 256, 0, stream>>>(x, wp, xp, N, NGB,
                                                row, col, E, gcursor, cbins, rbins, M, N);
    build_c<<<64, 512, 0, stream>>>(cbins, gcursor, coff, clist, M, E);
    aggm_buildr<<<64 + (M + 7) / 8, 512, 0, stream>>>(rbins, gcursor, roff, rlist, N, E,
                                                      xp, coff, clist, e_feat, M);
    gemm_mfma<1, false><<<(M + 127) / 128, 256, 0, stream>>>(e_feat, nullptr, wp + 16384, nullptr, e_proj, M);
    agg_mean<<<(N + 3) / 4, 256, 0, stream>>>(e_proj, roff, rlist, n_agg, N);
    gemm_mfma<2, true><<<(N + 127) / 128, 256, 0, stream>>>(xp, n_agg, wp + 32768, bu, out, N);
}